// Round 1
// baseline (341.319 us; speedup 1.0000x reference)
//
#include <hip/hip_runtime.h>
#include <math.h>

// ---------------------------------------------------------------------------
// MultiChannelAttention on MI355X (gfx950)
// out = softmax(causal(rope(xWq^T) rope(xWk^T)^T / sqrt(C))) (xWv^T) Wf^T + b
// B=4 T=2048 C=1024. All GEMMs in bf16 MFMA (16x16x32), fp32 accum,
// fp32 softmax. m97-style bt-GEMM: 128x128 tile, BK=32, global_load_lds w=16.
// Workspace layout (152 MB):
//   [0,16)MB xb  [16,24)MB Wq/Wk/Wv/Wf bf16  [24,40) Q  [40,56) K
//   [56,72) Vt  [72,88) O  [88,104) V (dead after transpose)
//   [88,152) S fp32 (P bf16 written in-place, row stride 8192B)
// ---------------------------------------------------------------------------

#define AS1(p) ((__attribute__((address_space(1))) void*)(p))
#define AS3(p) ((__attribute__((address_space(3))) void*)(p))

typedef __attribute__((ext_vector_type(8))) short bf16x8;
typedef __attribute__((ext_vector_type(4))) float f32x4;

__device__ __forceinline__ unsigned short f2bf(float f) {
  unsigned int u = __float_as_uint(f);
  u += 0x7fffu + ((u >> 16) & 1u);   // round-to-nearest-even
  return (unsigned short)(u >> 16);
}

// ---- fp32 -> bf16 cast, 4 elems/thread -----------------------------------
__global__ __launch_bounds__(256) void cast_f2b(const float* __restrict__ in,
                                                unsigned short* __restrict__ out,
                                                int n4) {
  int i = blockIdx.x * 256 + threadIdx.x;
  if (i >= n4) return;
  float4 f = ((const float4*)in)[i];
  ushort4 o;
  o.x = f2bf(f.x); o.y = f2bf(f.y); o.z = f2bf(f.z); o.w = f2bf(f.w);
  ((ushort4*)out)[i] = o;
}

// ---- core 128x128 bt-GEMM: C[m,n] = sum_k A[m,k]*B[n,k]; A,B bf16 K-fast --
__device__ __forceinline__ void gemm_core(const unsigned short* __restrict__ At, long long lda,
                                          const unsigned short* __restrict__ Bt, long long ldb,
                                          int K, f32x4 (&acc)[4][4],
                                          unsigned short* As, unsigned short* Bs) {
  const int tid  = threadIdx.x;
  const int lane = tid & 63;
  const int w    = tid >> 6;
  const int wm   = (w & 1) << 6;
  const int wn   = (w >> 1) << 6;
  const int fr   = lane & 15;   // A-frag row / B-frag col
  const int fq   = lane >> 4;   // k-quad
  const int srow = tid >> 2;
  const int scol = (tid & 3) << 3;
  const unsigned short* a0 = At + (long long)srow * lda + scol;
  const unsigned short* a1 = At + (long long)(srow + 64) * lda + scol;
  const unsigned short* b0 = Bt + (long long)srow * ldb + scol;
  const unsigned short* b1 = Bt + (long long)(srow + 64) * ldb + scol;
  unsigned short* As0 = As + srow * 32 + scol;
  unsigned short* As1 = As + (srow + 64) * 32 + scol;
  unsigned short* Bs0 = Bs + srow * 32 + scol;
  unsigned short* Bs1 = Bs + (srow + 64) * 32 + scol;
  for (int k0 = 0; k0 < K; k0 += 32) {
    __builtin_amdgcn_global_load_lds(AS1(a0 + k0), AS3(As0), 16, 0, 0);
    __builtin_amdgcn_global_load_lds(AS1(a1 + k0), AS3(As1), 16, 0, 0);
    __builtin_amdgcn_global_load_lds(AS1(b0 + k0), AS3(Bs0), 16, 0, 0);
    __builtin_amdgcn_global_load_lds(AS1(b1 + k0), AS3(Bs1), 16, 0, 0);
    __syncthreads();
    bf16x8 af[4], bf[4];
#pragma unroll
    for (int i = 0; i < 4; i++)
      af[i] = *(const bf16x8*)(As + (wm + i * 16 + fr) * 32 + fq * 8);
#pragma unroll
    for (int i = 0; i < 4; i++)
      bf[i] = *(const bf16x8*)(Bs + (wn + i * 16 + fr) * 32 + fq * 8);
#pragma unroll
    for (int mi = 0; mi < 4; mi++)
#pragma unroll
      for (int ni = 0; ni < 4; ni++)
        acc[mi][ni] = __builtin_amdgcn_mfma_f32_16x16x32_bf16(af[mi], bf[ni], acc[mi][ni], 0, 0, 0);
    __syncthreads();
  }
}

// ---- Q/K/V projections (+bias, +RoPE for Q/K), bf16 out -------------------
__global__ __launch_bounds__(256) void proj_rope(
    const unsigned short* __restrict__ xb,
    const unsigned short* __restrict__ Wq, const unsigned short* __restrict__ Wk,
    const unsigned short* __restrict__ Wv,
    const float* __restrict__ bq, const float* __restrict__ bk, const float* __restrict__ bv,
    unsigned short* __restrict__ Q, unsigned short* __restrict__ Ko,
    unsigned short* __restrict__ V) {
  __shared__ unsigned short As[128 * 32];
  __shared__ unsigned short Bs[128 * 32];
  const int m0 = blockIdx.x * 128;
  const int n0 = blockIdx.y * 128;
  const int which = blockIdx.z;
  const unsigned short* W = which == 0 ? Wq : (which == 1 ? Wk : Wv);
  const float* bias = which == 0 ? bq : (which == 1 ? bk : bv);
  unsigned short* Out = which == 0 ? Q : (which == 1 ? Ko : V);
  const bool rope = which < 2;

  f32x4 acc[4][4];
#pragma unroll
  for (int i = 0; i < 4; i++)
#pragma unroll
    for (int j = 0; j < 4; j++)
#pragma unroll
      for (int k = 0; k < 4; k++) acc[i][j][k] = 0.0f;

  gemm_core(xb + (long long)m0 * 1024, 1024, W + (long long)n0 * 1024, 1024, 1024, acc, As, Bs);

  const int tid = threadIdx.x, lane = tid & 63, w = tid >> 6;
  const int wm = (w & 1) << 6, wn = (w >> 1) << 6;
  const int cl = lane & 15, q4 = lane >> 4;
  const float L2T = 13.287712379549449f;  // log2(10000)
#pragma unroll
  for (int mi = 0; mi < 4; mi++)
#pragma unroll
    for (int ni = 0; ni < 4; ni++)
#pragma unroll
      for (int rr = 0; rr < 4; rr++) {
        int gm = m0 + wm + mi * 16 + q4 * 4 + rr;
        int gn = n0 + wn + ni * 16 + cl;
        float v = acc[mi][ni][rr] + bias[gn];
        if (rope) {
          float partner = __shfl_xor(v, 1, 64);  // pair element (adjacent col)
          int t = gm & 2047;
          int p = gn >> 1;
          float ang = (float)t * exp2f(-L2T * (float)(2 * p) * (1.0f / 1024.0f));
          float s, c;
          sincosf(ang, &s, &c);
          v = v * c + ((gn & 1) ? partner : -partner) * s;
        }
        Out[(long long)gm * 1024 + gn] = f2bf(v);
      }
}

// ---- V[b,s,d] -> Vt[b,d,s] ------------------------------------------------
__global__ __launch_bounds__(256) void transpose_v(const unsigned short* __restrict__ V,
                                                   unsigned short* __restrict__ Vt) {
  __shared__ unsigned short tle[64][65];
  const int b = blockIdx.z;
  const int s0 = blockIdx.x * 64, d0 = blockIdx.y * 64;
  const unsigned short* Vb = V + (long long)b * 2048 * 1024;
  unsigned short* Tb = Vt + (long long)b * 1024 * 2048;
  const int tid = threadIdx.x;
  union U { uint4 v; unsigned short u[8]; };
#pragma unroll
  for (int it = 0; it < 2; ++it) {
    int idx = tid + it * 256;
    int r = idx >> 3, c8 = (idx & 7) << 3;
    U d;
    d.v = *(const uint4*)(Vb + (long long)(s0 + r) * 1024 + d0 + c8);
#pragma unroll
    for (int j = 0; j < 8; j++) tle[r][c8 + j] = d.u[j];
  }
  __syncthreads();
#pragma unroll
  for (int it = 0; it < 2; ++it) {
    int idx = tid + it * 256;
    int r = idx >> 3, c8 = (idx & 7) << 3;
    U o;
#pragma unroll
    for (int j = 0; j < 8; j++) o.u[j] = tle[c8 + j][r];
    *(uint4*)(Tb + (long long)(d0 + r) * 2048 + s0 + c8) = o.v;
  }
}

// ---- S = Q K^T / sqrt(C), fp32, lower-triangular tiles only ---------------
__global__ __launch_bounds__(256) void score_gemm(const unsigned short* __restrict__ Q,
                                                  const unsigned short* __restrict__ Kk,
                                                  float* __restrict__ S) {
  if (blockIdx.y > blockIdx.x) return;  // tile fully above diagonal
  __shared__ unsigned short As[128 * 32];
  __shared__ unsigned short Bs[128 * 32];
  const int b = blockIdx.z;
  const int m0 = blockIdx.x * 128, n0 = blockIdx.y * 128;
  const unsigned short* Qb = Q + (long long)b * 2048 * 1024;
  const unsigned short* Kb = Kk + (long long)b * 2048 * 1024;
  float* Sb = S + (long long)b * 2048 * 2048;

  f32x4 acc[4][4];
#pragma unroll
  for (int i = 0; i < 4; i++)
#pragma unroll
    for (int j = 0; j < 4; j++)
#pragma unroll
      for (int k = 0; k < 4; k++) acc[i][j][k] = 0.0f;

  gemm_core(Qb + (long long)m0 * 1024, 1024, Kb + (long long)n0 * 1024, 1024, 1024, acc, As, Bs);

  const int tid = threadIdx.x, lane = tid & 63, w = tid >> 6;
  const int wm = (w & 1) << 6, wn = (w >> 1) << 6;
  const int cl = lane & 15, q4 = lane >> 4;
#pragma unroll
  for (int mi = 0; mi < 4; mi++)
#pragma unroll
    for (int ni = 0; ni < 4; ni++)
#pragma unroll
      for (int rr = 0; rr < 4; rr++) {
        int gm = m0 + wm + mi * 16 + q4 * 4 + rr;
        int gn = n0 + wn + ni * 16 + cl;
        // upper-triangle entries are garbage-allowed: softmax reads s<=t only
        Sb[(long long)gm * 2048 + gn] = acc[mi][ni][rr] * 0.03125f;
      }
}

// ---- per-row causal softmax; writes P bf16 in-place (row stride 8192 B) ---
__global__ __launch_bounds__(256) void softmax_rows(float* __restrict__ S) {
  __shared__ float red[8];
  const int rid = blockIdx.x;          // 0..8191 = b*2048 + t
  const int t = rid & 2047;
  float* row = S + (long long)rid * 2048;
  const int tid = threadIdx.x, lane = tid & 63, wid = tid >> 6;

  float4 v0 = ((const float4*)row)[tid];
  float4 v1 = ((const float4*)row)[tid + 256];
  float vv[8] = {v0.x, v0.y, v0.z, v0.w, v1.x, v1.y, v1.z, v1.w};
  int c0 = tid * 4, c1 = (tid + 256) * 4;
  int cidx[8] = {c0, c0 + 1, c0 + 2, c0 + 3, c1, c1 + 1, c1 + 2, c1 + 3};

  float mx = -INFINITY;
#pragma unroll
  for (int j = 0; j < 8; j++) {
    if (cidx[j] > t) vv[j] = -INFINITY;
    mx = fmaxf(mx, vv[j]);
  }
#pragma unroll
  for (int off = 1; off < 64; off <<= 1) mx = fmaxf(mx, __shfl_xor(mx, off, 64));
  if (lane == 0) red[wid] = mx;
  __syncthreads();
  mx = fmaxf(fmaxf(red[0], red[1]), fmaxf(red[2], red[3]));

  float e[8];
  float sum = 0.0f;
#pragma unroll
  for (int j = 0; j < 8; j++) {
    e[j] = (cidx[j] > t) ? 0.0f : __expf(vv[j] - mx);
    sum += e[j];
  }
#pragma unroll
  for (int off = 1; off < 64; off <<= 1) sum += __shfl_xor(sum, off, 64);
  if (lane == 0) red[4 + wid] = sum;
  __syncthreads();
  sum = red[4] + red[5] + red[6] + red[7];
  float inv = 1.0f / sum;

  unsigned short* prow = (unsigned short*)row;  // safe: this block read the whole row already
  ushort4 o0, o1;
  o0.x = f2bf(e[0] * inv); o0.y = f2bf(e[1] * inv); o0.z = f2bf(e[2] * inv); o0.w = f2bf(e[3] * inv);
  o1.x = f2bf(e[4] * inv); o1.y = f2bf(e[5] * inv); o1.z = f2bf(e[6] * inv); o1.w = f2bf(e[7] * inv);
  ((ushort4*)prow)[tid] = o0;
  ((ushort4*)prow)[tid + 256] = o1;
}

// ---- O = P V  (P bf16 over S storage, Vt pre-transposed), causal K-bound --
__global__ __launch_bounds__(256) void pv_gemm(const float* __restrict__ S,
                                               const unsigned short* __restrict__ Vt,
                                               unsigned short* __restrict__ O) {
  __shared__ unsigned short As[128 * 32];
  __shared__ unsigned short Bs[128 * 32];
  const int b = blockIdx.z;
  const int m0 = blockIdx.x * 128;  // t tile
  const int n0 = blockIdx.y * 128;  // d tile
  const unsigned short* Pb = (const unsigned short*)(S + (long long)b * 2048 * 2048);  // row stride 4096 elems
  const unsigned short* Vb = Vt + (long long)b * 1024 * 2048;
  const int K = m0 + 128;  // causal: P[t, s>t] == 0, t < m0+128

  f32x4 acc[4][4];
#pragma unroll
  for (int i = 0; i < 4; i++)
#pragma unroll
    for (int j = 0; j < 4; j++)
#pragma unroll
      for (int k = 0; k < 4; k++) acc[i][j][k] = 0.0f;

  gemm_core(Pb + (long long)m0 * 4096, 4096, Vb + (long long)n0 * 2048, 2048, K, acc, As, Bs);

  const int tid = threadIdx.x, lane = tid & 63, w = tid >> 6;
  const int wm = (w & 1) << 6, wn = (w >> 1) << 6;
  const int cl = lane & 15, q4 = lane >> 4;
#pragma unroll
  for (int mi = 0; mi < 4; mi++)
#pragma unroll
    for (int ni = 0; ni < 4; ni++)
#pragma unroll
      for (int rr = 0; rr < 4; rr++) {
        int gm = m0 + wm + mi * 16 + q4 * 4 + rr;
        int gn = n0 + wn + ni * 16 + cl;
        O[((long long)b * 2048 + gm) * 1024 + gn] = f2bf(acc[mi][ni][rr]);
      }
}

// ---- out = O Wf^T + bf, fp32 out ------------------------------------------
__global__ __launch_bounds__(256) void final_gemm(const unsigned short* __restrict__ O,
                                                  const unsigned short* __restrict__ Wf,
                                                  const float* __restrict__ bf_,
                                                  float* __restrict__ out) {
  __shared__ unsigned short As[128 * 32];
  __shared__ unsigned short Bs[128 * 32];
  const int m0 = blockIdx.x * 128;
  const int n0 = blockIdx.y * 128;

  f32x4 acc[4][4];
#pragma unroll
  for (int i = 0; i < 4; i++)
#pragma unroll
    for (int j = 0; j < 4; j++)
#pragma unroll
      for (int k = 0; k < 4; k++) acc[i][j][k] = 0.0f;

  gemm_core(O + (long long)m0 * 1024, 1024, Wf + (long long)n0 * 1024, 1024, 1024, acc, As, Bs);

  const int tid = threadIdx.x, lane = tid & 63, w = tid >> 6;
  const int wm = (w & 1) << 6, wn = (w >> 1) << 6;
  const int cl = lane & 15, q4 = lane >> 4;
#pragma unroll
  for (int mi = 0; mi < 4; mi++)
#pragma unroll
    for (int ni = 0; ni < 4; ni++)
#pragma unroll
      for (int rr = 0; rr < 4; rr++) {
        int gm = m0 + wm + mi * 16 + q4 * 4 + rr;
        int gn = n0 + wn + ni * 16 + cl;
        out[(long long)gm * 1024 + gn] = acc[mi][ni][rr] + bf_[gn];
      }
}

// ---------------------------------------------------------------------------
extern "C" void kernel_launch(void* const* d_in, const int* in_sizes, int n_in,
                              void* d_out, int out_size, void* d_ws, size_t ws_size,
                              hipStream_t stream) {
  (void)in_sizes; (void)n_in; (void)out_size; (void)ws_size;
  const float* x   = (const float*)d_in[0];
  const float* Wq  = (const float*)d_in[1];
  const float* bq  = (const float*)d_in[2];
  const float* Wk  = (const float*)d_in[3];
  const float* bk  = (const float*)d_in[4];
  const float* Wv  = (const float*)d_in[5];
  const float* bv  = (const float*)d_in[6];
  const float* Wf  = (const float*)d_in[7];
  const float* bf_ = (const float*)d_in[8];
  float* out = (float*)d_out;

  char* ws = (char*)d_ws;
  const size_t MB = 1024 * 1024;
  unsigned short* xb  = (unsigned short*)(ws);             // 16 MB
  unsigned short* Wqb = (unsigned short*)(ws + 16 * MB);   // 2 MB
  unsigned short* Wkb = (unsigned short*)(ws + 18 * MB);   // 2 MB
  unsigned short* Wvb = (unsigned short*)(ws + 20 * MB);   // 2 MB
  unsigned short* Wfb = (unsigned short*)(ws + 22 * MB);   // 2 MB
  unsigned short* Qb  = (unsigned short*)(ws + 24 * MB);   // 16 MB
  unsigned short* Kb  = (unsigned short*)(ws + 40 * MB);   // 16 MB
  unsigned short* Vtb = (unsigned short*)(ws + 56 * MB);   // 16 MB
  unsigned short* Ob  = (unsigned short*)(ws + 72 * MB);   // 16 MB
  unsigned short* Vb  = (unsigned short*)(ws + 88 * MB);   // 16 MB (dead after transpose)
  float*          S   = (float*)(ws + 88 * MB);            // 64 MB (overwrites V; P in-place)

  dim3 blk(256);
  // bf16 casts
  cast_f2b<<<dim3(2097152 / 256), blk, 0, stream>>>(x, xb, 2097152);
  cast_f2b<<<dim3(262144 / 256), blk, 0, stream>>>(Wq, Wqb, 262144);
  cast_f2b<<<dim3(262144 / 256), blk, 0, stream>>>(Wk, Wkb, 262144);
  cast_f2b<<<dim3(262144 / 256), blk, 0, stream>>>(Wv, Wvb, 262144);
  cast_f2b<<<dim3(262144 / 256), blk, 0, stream>>>(Wf, Wfb, 262144);
  // Q/K/V projections (+RoPE on Q,K)
  proj_rope<<<dim3(64, 8, 3), blk, 0, stream>>>(xb, Wqb, Wkb, Wvb, bq, bk, bv, Qb, Kb, Vb);
  // V transpose for PV bt-GEMM
  transpose_v<<<dim3(32, 16, 4), blk, 0, stream>>>(Vb, Vtb);
  // scores (lower-triangular tiles), fp32
  score_gemm<<<dim3(16, 16, 4), blk, 0, stream>>>(Qb, Kb, S);
  // causal softmax -> P bf16 in-place
  softmax_rows<<<dim3(8192), blk, 0, stream>>>(S);
  // O = P V
  pv_gemm<<<dim3(16, 8, 4), blk, 0, stream>>>(S, Vtb, Ob);
  // out = O Wf^T + bf
  final_gemm<<<dim3(64, 8), blk, 0, stream>>>(Ob, Wfb, bf_, out);
}

// Round 2
// 334.853 us; speedup vs baseline: 1.0193x; 1.0193x over previous
//
#include <hip/hip_runtime.h>
#include <math.h>

// ---------------------------------------------------------------------------
// MultiChannelAttention on MI355X (gfx950)
// out = softmax(causal(rope(xWq^T) rope(xWk^T)^T / sqrt(C))) (xWv^T) Wf^T + b
// B=4 T=2048 C=1024. bf16 MFMA (16x16x32) GEMMs, fp32 accum/softmax.
// R1: RoPE via precomputed (cos,sin) table (kills libm sincos in epilogue);
//     XOR-swizzled LDS K-groups (kills ds_read_b128 bank conflicts);
//     causal-bounded softmax; merged casts.
// Workspace layout (152 MB):
//   [0,16)MB xb  [16,24)MB Wq/Wk/Wv/Wf bf16  [24,40) Q  [40,56) K
//   [56,72) Vt  [72,88) O  [88,104) V (dead after transpose)
//   [104,112) rope table (dead after proj)  [88,152) S fp32 (P bf16 in-place)
// ---------------------------------------------------------------------------

#define AS1(p) ((__attribute__((address_space(1))) void*)(p))
#define AS3(p) ((__attribute__((address_space(3))) void*)(p))

typedef __attribute__((ext_vector_type(8))) short bf16x8;
typedef __attribute__((ext_vector_type(4))) float f32x4;

__device__ __forceinline__ unsigned short f2bf(float f) {
  unsigned int u = __float_as_uint(f);
  u += 0x7fffu + ((u >> 16) & 1u);   // round-to-nearest-even
  return (unsigned short)(u >> 16);
}

// ---- fp32 -> bf16 cast for x + 4 weight matrices, one launch --------------
__global__ __launch_bounds__(256) void cast_all(
    const float* __restrict__ x, const float* __restrict__ Wq,
    const float* __restrict__ Wk, const float* __restrict__ Wv,
    const float* __restrict__ Wf,
    unsigned short* __restrict__ xb, unsigned short* __restrict__ Wqb,
    unsigned short* __restrict__ Wkb, unsigned short* __restrict__ Wvb,
    unsigned short* __restrict__ Wfb) {
  int i = blockIdx.x * 256 + threadIdx.x;           // float4 index
  const float* src; unsigned short* dst; int off;
  if (i < 2097152) { src = x; dst = xb; off = i; }
  else {
    int j = i - 2097152;
    int w = j >> 18; off = j & 262143;              // 262144 float4 per W
    src = (w == 0) ? Wq : (w == 1) ? Wk : (w == 2) ? Wv : Wf;
    dst = (w == 0) ? Wqb : (w == 1) ? Wkb : (w == 2) ? Wvb : Wfb;
  }
  float4 f = ((const float4*)src)[off];
  ushort4 o;
  o.x = f2bf(f.x); o.y = f2bf(f.y); o.z = f2bf(f.z); o.w = f2bf(f.w);
  ((ushort4*)dst)[off] = o;
}

// ---- RoPE (cos,sin) table: tab[t*512+p], t in [0,2048), p in [0,512) ------
__global__ __launch_bounds__(256) void rope_table(float2* __restrict__ tab) {
  int idx = blockIdx.x * 256 + threadIdx.x;   // 1048576 entries
  int t = idx >> 9, p = idx & 511;
  const float L2T = 13.287712379549449f;      // log2(10000)
  float freq = exp2f(-L2T * (float)(2 * p) * (1.0f / 1024.0f));
  float ang = (float)t * freq;
  float s, c;
  sincosf(ang, &s, &c);                        // accurate; one-time cost
  tab[idx] = make_float2(c, s);
}

// ---- core 128x128 bt-GEMM: C[m,n] = sum_k A[m,k]*B[n,k]; A,B bf16 K-fast --
// LDS K-group XOR swizzle: physical col-group cg holds logical group
// cg ^ ((row>>1)&3). global_load_lds dest stays tid*16 (wave-uniform+lane*16).
__device__ __forceinline__ void gemm_core(const unsigned short* __restrict__ At, long long lda,
                                          const unsigned short* __restrict__ Bt, long long ldb,
                                          int K, f32x4 (&acc)[4][4],
                                          unsigned short* As, unsigned short* Bs) {
  const int tid  = threadIdx.x;
  const int lane = tid & 63;
  const int w    = tid >> 6;
  const int wm   = (w & 1) << 6;
  const int wn   = (w >> 1) << 6;
  const int fr   = lane & 15;   // A-frag row / B-frag col
  const int fq   = lane >> 4;   // k-quad (logical)
  const int srow = tid >> 2;
  const int scol = (tid & 3) << 3;                       // physical col group*8
  const int lg   = ((tid & 3) ^ ((srow >> 1) & 3)) << 3; // logical cols loaded
  const unsigned short* a0 = At + (long long)srow * lda + lg;
  const unsigned short* a1 = At + (long long)(srow + 64) * lda + lg; // same swizzle: +64 rows keeps (row>>1)&3
  const unsigned short* b0 = Bt + (long long)srow * ldb + lg;
  const unsigned short* b1 = Bt + (long long)(srow + 64) * ldb + lg;
  unsigned short* As0 = As + srow * 32 + scol;
  unsigned short* As1 = As + (srow + 64) * 32 + scol;
  unsigned short* Bs0 = Bs + srow * 32 + scol;
  unsigned short* Bs1 = Bs + (srow + 64) * 32 + scol;
  const int pg = (fq ^ ((fr >> 1) & 3)) << 3;            // physical group for reads
  for (int k0 = 0; k0 < K; k0 += 32) {
    __builtin_amdgcn_global_load_lds(AS1(a0 + k0), AS3(As0), 16, 0, 0);
    __builtin_amdgcn_global_load_lds(AS1(a1 + k0), AS3(As1), 16, 0, 0);
    __builtin_amdgcn_global_load_lds(AS1(b0 + k0), AS3(Bs0), 16, 0, 0);
    __builtin_amdgcn_global_load_lds(AS1(b1 + k0), AS3(Bs1), 16, 0, 0);
    __syncthreads();
    bf16x8 af[4], bfr[4];
#pragma unroll
    for (int i = 0; i < 4; i++)
      af[i] = *(const bf16x8*)(As + (wm + i * 16 + fr) * 32 + pg);
#pragma unroll
    for (int i = 0; i < 4; i++)
      bfr[i] = *(const bf16x8*)(Bs + (wn + i * 16 + fr) * 32 + pg);
#pragma unroll
    for (int mi = 0; mi < 4; mi++)
#pragma unroll
      for (int ni = 0; ni < 4; ni++)
        acc[mi][ni] = __builtin_amdgcn_mfma_f32_16x16x32_bf16(af[mi], bfr[ni], acc[mi][ni], 0, 0, 0);
    __syncthreads();
  }
}

// ---- Q/K/V projections (+bias, +RoPE for Q/K via table), bf16 out ---------
__global__ __launch_bounds__(256) void proj_rope(
    const unsigned short* __restrict__ xb,
    const unsigned short* __restrict__ Wq, const unsigned short* __restrict__ Wk,
    const unsigned short* __restrict__ Wv,
    const float* __restrict__ bq, const float* __restrict__ bk, const float* __restrict__ bv,
    const float2* __restrict__ tab,
    unsigned short* __restrict__ Q, unsigned short* __restrict__ Ko,
    unsigned short* __restrict__ V) {
  __shared__ unsigned short As[128 * 32];
  __shared__ unsigned short Bs[128 * 32];
  const int m0 = blockIdx.x * 128;
  const int n0 = blockIdx.y * 128;
  const int which = blockIdx.z;
  const unsigned short* W = which == 0 ? Wq : (which == 1 ? Wk : Wv);
  const float* bias = which == 0 ? bq : (which == 1 ? bk : bv);
  unsigned short* Out = which == 0 ? Q : (which == 1 ? Ko : V);
  const bool rope = which < 2;

  f32x4 acc[4][4];
#pragma unroll
  for (int i = 0; i < 4; i++)
#pragma unroll
    for (int j = 0; j < 4; j++)
#pragma unroll
      for (int k = 0; k < 4; k++) acc[i][j][k] = 0.0f;

  gemm_core(xb + (long long)m0 * 1024, 1024, W + (long long)n0 * 1024, 1024, 1024, acc, As, Bs);

  const int tid = threadIdx.x, lane = tid & 63, w = tid >> 6;
  const int wm = (w & 1) << 6, wn = (w >> 1) << 6;
  const int cl = lane & 15, q4 = lane >> 4;
#pragma unroll
  for (int mi = 0; mi < 4; mi++)
#pragma unroll
    for (int ni = 0; ni < 4; ni++)
#pragma unroll
      for (int rr = 0; rr < 4; rr++) {
        int gm = m0 + wm + mi * 16 + q4 * 4 + rr;
        int gn = n0 + wn + ni * 16 + cl;
        float v = acc[mi][ni][rr] + bias[gn];
        if (rope) {
          float partner = __shfl_xor(v, 1, 64);  // pair element (adjacent col)
          int t = gm & 2047;
          int p = gn >> 1;
          float2 cs = tab[t * 512 + p];
          v = v * cs.x + ((gn & 1) ? partner : -partner) * cs.y;
        }
        Out[(long long)gm * 1024 + gn] = f2bf(v);
      }
}

// ---- V[b,s,d] -> Vt[b,d,s] ------------------------------------------------
__global__ __launch_bounds__(256) void transpose_v(const unsigned short* __restrict__ V,
                                                   unsigned short* __restrict__ Vt) {
  __shared__ unsigned short tle[64][65];
  const int b = blockIdx.z;
  const int s0 = blockIdx.x * 64, d0 = blockIdx.y * 64;
  const unsigned short* Vb = V + (long long)b * 2048 * 1024;
  unsigned short* Tb = Vt + (long long)b * 1024 * 2048;
  const int tid = threadIdx.x;
  union U { uint4 v; unsigned short u[8]; };
#pragma unroll
  for (int it = 0; it < 2; ++it) {
    int idx = tid + it * 256;
    int r = idx >> 3, c8 = (idx & 7) << 3;
    U d;
    d.v = *(const uint4*)(Vb + (long long)(s0 + r) * 1024 + d0 + c8);
#pragma unroll
    for (int j = 0; j < 8; j++) tle[r][c8 + j] = d.u[j];
  }
  __syncthreads();
#pragma unroll
  for (int it = 0; it < 2; ++it) {
    int idx = tid + it * 256;
    int r = idx >> 3, c8 = (idx & 7) << 3;
    U o;
#pragma unroll
    for (int j = 0; j < 8; j++) o.u[j] = tle[c8 + j][r];
    *(uint4*)(Tb + (long long)(d0 + r) * 2048 + s0 + c8) = o.v;
  }
}

// ---- S = Q K^T / sqrt(C), fp32, lower-triangular tiles only ---------------
__global__ __launch_bounds__(256) void score_gemm(const unsigned short* __restrict__ Q,
                                                  const unsigned short* __restrict__ Kk,
                                                  float* __restrict__ S) {
  if (blockIdx.y > blockIdx.x) return;  // tile fully above diagonal
  __shared__ unsigned short As[128 * 32];
  __shared__ unsigned short Bs[128 * 32];
  const int b = blockIdx.z;
  const int m0 = blockIdx.x * 128, n0 = blockIdx.y * 128;
  const unsigned short* Qb = Q + (long long)b * 2048 * 1024;
  const unsigned short* Kb = Kk + (long long)b * 2048 * 1024;
  float* Sb = S + (long long)b * 2048 * 2048;

  f32x4 acc[4][4];
#pragma unroll
  for (int i = 0; i < 4; i++)
#pragma unroll
    for (int j = 0; j < 4; j++)
#pragma unroll
      for (int k = 0; k < 4; k++) acc[i][j][k] = 0.0f;

  gemm_core(Qb + (long long)m0 * 1024, 1024, Kb + (long long)n0 * 1024, 1024, 1024, acc, As, Bs);

  const int tid = threadIdx.x, lane = tid & 63, w = tid >> 6;
  const int wm = (w & 1) << 6, wn = (w >> 1) << 6;
  const int cl = lane & 15, q4 = lane >> 4;
#pragma unroll
  for (int mi = 0; mi < 4; mi++)
#pragma unroll
    for (int ni = 0; ni < 4; ni++)
#pragma unroll
      for (int rr = 0; rr < 4; rr++) {
        int gm = m0 + wm + mi * 16 + q4 * 4 + rr;
        int gn = n0 + wn + ni * 16 + cl;
        // upper-triangle entries are garbage-allowed: softmax reads s<=t only
        Sb[(long long)gm * 2048 + gn] = acc[mi][ni][rr] * 0.03125f;
      }
}

// ---- per-row causal softmax; writes P bf16 in-place (row stride 8192 B) ---
// Reads only chunks with col <= t; zero-fills up to the 128-aligned boundary
// that pv_gemm will read.
__global__ __launch_bounds__(256) void softmax_rows(float* __restrict__ S) {
  __shared__ float red[8];
  const int rid = blockIdx.x;          // 0..8191 = b*2048 + t
  const int t = rid & 2047;
  float* row = S + (long long)rid * 2048;
  const int tid = threadIdx.x, lane = tid & 63, wid = tid >> 6;
  const int lastc = t >> 2;                       // chunk containing t
  const int wchunks = ((t >> 7) + 1) << 5;        // chunks pv_gemm reads

  float4 v0 = make_float4(0.f, 0.f, 0.f, 0.f), v1 = v0;
  if (tid <= lastc)       v0 = ((const float4*)row)[tid];
  if (tid + 256 <= lastc) v1 = ((const float4*)row)[tid + 256];
  float vv[8] = {v0.x, v0.y, v0.z, v0.w, v1.x, v1.y, v1.z, v1.w};
  int c0 = tid * 4, c1 = (tid + 256) * 4;
  int cidx[8] = {c0, c0 + 1, c0 + 2, c0 + 3, c1, c1 + 1, c1 + 2, c1 + 3};

  float mx = -INFINITY;
#pragma unroll
  for (int j = 0; j < 8; j++) {
    if (cidx[j] > t) vv[j] = -INFINITY;
    mx = fmaxf(mx, vv[j]);
  }
#pragma unroll
  for (int off = 1; off < 64; off <<= 1) mx = fmaxf(mx, __shfl_xor(mx, off, 64));
  if (lane == 0) red[wid] = mx;
  __syncthreads();
  mx = fmaxf(fmaxf(red[0], red[1]), fmaxf(red[2], red[3]));

  float e[8];
  float sum = 0.0f;
#pragma unroll
  for (int j = 0; j < 8; j++) {
    e[j] = (cidx[j] > t) ? 0.0f : __expf(vv[j] - mx);
    sum += e[j];
  }
#pragma unroll
  for (int off = 1; off < 64; off <<= 1) sum += __shfl_xor(sum, off, 64);
  if (lane == 0) red[4 + wid] = sum;
  __syncthreads();
  sum = red[4] + red[5] + red[6] + red[7];
  float inv = 1.0f / sum;

  unsigned short* prow = (unsigned short*)row;  // safe: reads of this row done
  ushort4 o0, o1;
  o0.x = f2bf(e[0] * inv); o0.y = f2bf(e[1] * inv); o0.z = f2bf(e[2] * inv); o0.w = f2bf(e[3] * inv);
  o1.x = f2bf(e[4] * inv); o1.y = f2bf(e[5] * inv); o1.z = f2bf(e[6] * inv); o1.w = f2bf(e[7] * inv);
  if (tid < wchunks)       ((ushort4*)prow)[tid] = o0;
  if (tid + 256 < wchunks) ((ushort4*)prow)[tid + 256] = o1;
}

// ---- O = P V  (P bf16 over S storage, Vt pre-transposed), causal K-bound --
__global__ __launch_bounds__(256) void pv_gemm(const float* __restrict__ S,
                                               const unsigned short* __restrict__ Vt,
                                               unsigned short* __restrict__ O) {
  __shared__ unsigned short As[128 * 32];
  __shared__ unsigned short Bs[128 * 32];
  const int b = blockIdx.z;
  const int m0 = blockIdx.x * 128;  // t tile
  const int n0 = blockIdx.y * 128;  // d tile
  const unsigned short* Pb = (const unsigned short*)(S + (long long)b * 2048 * 2048);  // row stride 4096 elems
  const unsigned short* Vb = Vt + (long long)b * 1024 * 2048;
  const int K = m0 + 128;  // causal: P[t, s>t] == 0, t < m0+128

  f32x4 acc[4][4];
#pragma unroll
  for (int i = 0; i < 4; i++)
#pragma unroll
    for (int j = 0; j < 4; j++)
#pragma unroll
      for (int k = 0; k < 4; k++) acc[i][j][k] = 0.0f;

  gemm_core(Pb + (long long)m0 * 4096, 4096, Vb + (long long)n0 * 2048, 2048, K, acc, As, Bs);

  const int tid = threadIdx.x, lane = tid & 63, w = tid >> 6;
  const int wm = (w & 1) << 6, wn = (w >> 1) << 6;
  const int cl = lane & 15, q4 = lane >> 4;
#pragma unroll
  for (int mi = 0; mi < 4; mi++)
#pragma unroll
    for (int ni = 0; ni < 4; ni++)
#pragma unroll
      for (int rr = 0; rr < 4; rr++) {
        int gm = m0 + wm + mi * 16 + q4 * 4 + rr;
        int gn = n0 + wn + ni * 16 + cl;
        O[((long long)b * 2048 + gm) * 1024 + gn] = f2bf(acc[mi][ni][rr]);
      }
}

// ---- out = O Wf^T + bf, fp32 out ------------------------------------------
__global__ __launch_bounds__(256) void final_gemm(const unsigned short* __restrict__ O,
                                                  const unsigned short* __restrict__ Wf,
                                                  const float* __restrict__ bf_,
                                                  float* __restrict__ out) {
  __shared__ unsigned short As[128 * 32];
  __shared__ unsigned short Bs[128 * 32];
  const int m0 = blockIdx.x * 128;
  const int n0 = blockIdx.y * 128;

  f32x4 acc[4][4];
#pragma unroll
  for (int i = 0; i < 4; i++)
#pragma unroll
    for (int j = 0; j < 4; j++)
#pragma unroll
      for (int k = 0; k < 4; k++) acc[i][j][k] = 0.0f;

  gemm_core(O + (long long)m0 * 1024, 1024, Wf + (long long)n0 * 1024, 1024, 1024, acc, As, Bs);

  const int tid = threadIdx.x, lane = tid & 63, w = tid >> 6;
  const int wm = (w & 1) << 6, wn = (w >> 1) << 6;
  const int cl = lane & 15, q4 = lane >> 4;
#pragma unroll
  for (int mi = 0; mi < 4; mi++)
#pragma unroll
    for (int ni = 0; ni < 4; ni++)
#pragma unroll
      for (int rr = 0; rr < 4; rr++) {
        int gm = m0 + wm + mi * 16 + q4 * 4 + rr;
        int gn = n0 + wn + ni * 16 + cl;
        out[(long long)gm * 1024 + gn] = acc[mi][ni][rr] + bf_[gn];
      }
}

// ---------------------------------------------------------------------------
extern "C" void kernel_launch(void* const* d_in, const int* in_sizes, int n_in,
                              void* d_out, int out_size, void* d_ws, size_t ws_size,
                              hipStream_t stream) {
  (void)in_sizes; (void)n_in; (void)out_size; (void)ws_size;
  const float* x   = (const float*)d_in[0];
  const float* Wq  = (const float*)d_in[1];
  const float* bq  = (const float*)d_in[2];
  const float* Wk  = (const float*)d_in[3];
  const float* bk  = (const float*)d_in[4];
  const float* Wv  = (const float*)d_in[5];
  const float* bv  = (const float*)d_in[6];
  const float* Wf  = (const float*)d_in[7];
  const float* bf_ = (const float*)d_in[8];
  float* out = (float*)d_out;

  char* ws = (char*)d_ws;
  const size_t MB = 1024 * 1024;
  unsigned short* xb  = (unsigned short*)(ws);             // 16 MB
  unsigned short* Wqb = (unsigned short*)(ws + 16 * MB);   // 2 MB
  unsigned short* Wkb = (unsigned short*)(ws + 18 * MB);   // 2 MB
  unsigned short* Wvb = (unsigned short*)(ws + 20 * MB);   // 2 MB
  unsigned short* Wfb = (unsigned short*)(ws + 22 * MB);   // 2 MB
  unsigned short* Qb  = (unsigned short*)(ws + 24 * MB);   // 16 MB
  unsigned short* Kb  = (unsigned short*)(ws + 40 * MB);   // 16 MB
  unsigned short* Vtb = (unsigned short*)(ws + 56 * MB);   // 16 MB
  unsigned short* Ob  = (unsigned short*)(ws + 72 * MB);   // 16 MB
  unsigned short* Vb  = (unsigned short*)(ws + 88 * MB);   // 16 MB (dead after transpose)
  float2*         tab = (float2*)(ws + 104 * MB);          // 8 MB (dead after proj; S overwrites)
  float*          S   = (float*)(ws + 88 * MB);            // 64 MB (overwrites V+tab; P in-place)

  dim3 blk(256);
  // bf16 casts (x + 4 weights) in one launch
  cast_all<<<dim3(3145728 / 256), blk, 0, stream>>>(x, Wq, Wk, Wv, Wf, xb, Wqb, Wkb, Wvb, Wfb);
  // RoPE cos/sin table
  rope_table<<<dim3(1048576 / 256), blk, 0, stream>>>(tab);
  // Q/K/V projections (+RoPE on Q,K)
  proj_rope<<<dim3(64, 8, 3), blk, 0, stream>>>(xb, Wqb, Wkb, Wvb, bq, bk, bv, tab, Qb, Kb, Vb);
  // V transpose for PV bt-GEMM
  transpose_v<<<dim3(32, 16, 4), blk, 0, stream>>>(Vb, Vtb);
  // scores (lower-triangular tiles), fp32
  score_gemm<<<dim3(16, 16, 4), blk, 0, stream>>>(Qb, Kb, S);
  // causal softmax -> P bf16 in-place
  softmax_rows<<<dim3(8192), blk, 0, stream>>>(S);
  // O = P V
  pv_gemm<<<dim3(16, 8, 4), blk, 0, stream>>>(S, Vtb, Ob);
  // out = O Wf^T + bf
  final_gemm<<<dim3(64, 8), blk, 0, stream>>>(Ob, Wfb, bf_, out);
}